// Round 9
// baseline (1005.614 us; speedup 1.0000x reference)
//
#include <hip/hip_runtime.h>
#include <hip/hip_fp16.h>

#define BP_EPS 1e-12f
#define BP_K 8
#define LOG_C 2.0f      // centering offset: stored = log(m) + LOG_C
#define BSH 6           // nodes per bucket = 64
#define BNODES 64
#define NB1 512         // edge chunks (blocks) for hist + scatter

typedef __attribute__((ext_vector_type(8))) _Float16 half8;

// ===========================================================================
// Build: group directed edges by destination node WITHOUT global atomics.
// Payload encoding: at node u (=src) the incoming direction is (v->u) =
// (e<<1)|1 (msgs row e+Eu); at node v it's (u->v) = (e<<1)|0 (msgs row e).
// k_csr emits pos[payload] = slot and eid[slot] = msgs-row-id.
// k_ro derives RO[s] = (rev[s], oth[s]) where oth[s] is the node whose
// aggregate S produces the NEW message landing at slot s (pull form).
// Messages LIVE in CSR slot order: reduce reads sequentially; emit gathers
// Wc[rev[s]] (L3-backed) and writes Wn[s] sequentially -- NO scatter stores
// in any hot kernel.
// ===========================================================================

__global__ void k_hist(const int* __restrict__ src, const int* __restrict__ dst,
                       int* __restrict__ G, int Eu, int nbuck) {
    extern __shared__ int h[];
    for (int i = threadIdx.x; i < nbuck; i += blockDim.x) h[i] = 0;
    __syncthreads();
    int per = (Eu + NB1 - 1) / NB1;
    int s0 = blockIdx.x * per;
    int s1 = min(s0 + per, Eu);
    for (int e = s0 + threadIdx.x; e < s1; e += blockDim.x) {
        atomicAdd(&h[src[e] >> BSH], 1);
        atomicAdd(&h[dst[e] >> BSH], 1);
    }
    __syncthreads();
    for (int b = threadIdx.x; b < nbuck; b += blockDim.x)
        G[blockIdx.x * nbuck + b] = h[b];
}

__global__ void k_scanG(const int* __restrict__ G, int* __restrict__ Gpre,
                        int* __restrict__ total, int nbuck) {
    __shared__ int buf[NB1];
    int b = blockIdx.x;
    int t = threadIdx.x;
    int v = G[t * nbuck + b];
    buf[t] = v;
    __syncthreads();
    for (int off = 1; off < NB1; off <<= 1) {
        int x = (t >= off) ? buf[t - off] : 0;
        __syncthreads();
        buf[t] += x;
        __syncthreads();
    }
    Gpre[b * NB1 + t] = buf[t] - v;
    if (t == NB1 - 1) total[b] = buf[t];
}

__global__ void k_scanT(const int* __restrict__ total, int* __restrict__ base,
                        int nbuck, int* __restrict__ row_n, int E) {
    __shared__ int buf[1024];
    int t = threadIdx.x;
    int carry = 0;
    for (int s = 0; s < nbuck; s += 1024) {
        int i = s + t;
        int v = (i < nbuck) ? total[i] : 0;
        buf[t] = v;
        __syncthreads();
        for (int off = 1; off < 1024; off <<= 1) {
            int x = (t >= off) ? buf[t - off] : 0;
            __syncthreads();
            buf[t] += x;
            __syncthreads();
        }
        if (i < nbuck) base[i] = carry + buf[t] - v;
        carry += buf[1023];
        __syncthreads();
    }
    if (t == 0) { base[nbuck] = carry; *row_n = E; }
}

__global__ void k_scatter(const int* __restrict__ src, const int* __restrict__ dst,
                          const int* __restrict__ Gpre, const int* __restrict__ base,
                          int2* __restrict__ items, int Eu, int nbuck) {
    extern __shared__ int cur[];
    int blk = blockIdx.x;
    for (int i = threadIdx.x; i < nbuck; i += blockDim.x)
        cur[i] = base[i] + Gpre[i * NB1 + blk];
    __syncthreads();
    int per = (Eu + NB1 - 1) / NB1;
    int s0 = blk * per;
    int s1 = min(s0 + per, Eu);
    for (int e = s0 + threadIdx.x; e < s1; e += blockDim.x) {
        int u = src[e], v = dst[e];
        int pu = atomicAdd(&cur[u >> BSH], 1);
        items[pu] = make_int2(u, (e << 1) | 1);
        int pv = atomicAdd(&cur[v >> BSH], 1);
        items[pv] = make_int2(v, (e << 1) | 0);
    }
}

// bucket -> per-node CSR; emit pos[payload] = slot, eid[slot] = msgs row id.
__global__ void k_csr(const int2* __restrict__ items, const int* __restrict__ base,
                      int* __restrict__ row, int* __restrict__ pos,
                      int* __restrict__ eid, int n, int Eu) {
    __shared__ int deg[BNODES];
    __shared__ int cur[BNODES];
    int b = blockIdx.x;
    int lo = base[b], hi = base[b + 1];
    int node0 = b << BSH;
    if (threadIdx.x < BNODES) deg[threadIdx.x] = 0;
    __syncthreads();
    for (int i = lo + threadIdx.x; i < hi; i += blockDim.x)
        atomicAdd(&deg[items[i].x - node0], 1);
    __syncthreads();
    if (threadIdx.x == 0) {
        int acc = 0;
        for (int t = 0; t < BNODES; ++t) { int d = deg[t]; deg[t] = acc; acc += d; }
    }
    __syncthreads();
    if (threadIdx.x < BNODES) {
        int node = node0 + threadIdx.x;
        if (node < n) row[node] = lo + deg[threadIdx.x];
        cur[threadIdx.x] = deg[threadIdx.x];
    }
    __syncthreads();
    for (int i = lo + threadIdx.x; i < hi; i += blockDim.x) {
        int2 x = items[i];
        int p = atomicAdd(&cur[x.x - node0], 1);
        int slot = lo + p;
        pos[x.y] = slot;
        eid[slot] = (x.y >> 1) + (x.y & 1) * Eu;
    }
}

// RO[s] = (rev[s], oth[s]). Slot pos[2e] holds (u->v) at node v: its NEW
// value comes from S[u] minus Wc[pos[2e+1]]. Symmetric for pos[2e+1].
__global__ void k_ro(const int* __restrict__ pos, const int* __restrict__ src,
                     const int* __restrict__ dst, int2* __restrict__ RO, int Eu) {
    int e = blockIdx.x * blockDim.x + threadIdx.x;
    if (e < Eu) {
        int2 p = ((const int2*)pos)[e];
        RO[p.x] = make_int2(p.y, src[e]);
        RO[p.y] = make_int2(p.x, dst[e]);
    }
}

// LP[i][k] = log(max(prior, eps)) -- folded into the aggregate S once.
__global__ void k_lp(const float* __restrict__ prior, float* __restrict__ LP, int n8) {
    int i = blockIdx.x * blockDim.x + threadIdx.x;
    if (i < n8) LP[i] = __logf(fmaxf(prior[i], BP_EPS));
}

// Gather-permute: thread per SLOT, read msgs[eid[s]] (scattered, L3-warm),
// write fp16 centered-log W[s] SEQUENTIALLY (full-line stores).
__global__ void __launch_bounds__(256) k_perm(
        const float* __restrict__ msgs, const int* __restrict__ eid,
        _Float16* __restrict__ W, int E) {
    int s = blockIdx.x * blockDim.x + threadIdx.x;
    if (s >= E) return;
    int id = eid[s];
    const float4* m4 = (const float4*)(msgs + (size_t)id * BP_K);
    float4 x = m4[0], y = m4[1];
    float v[BP_K] = {x.x, x.y, x.z, x.w, y.x, y.y, y.z, y.w};
    half8 o;
#pragma unroll
    for (int k = 0; k < BP_K; ++k)
        o[k] = (_Float16)(__logf(fmaxf(v[k], BP_EPS)) + LOG_C);
    *(half8*)(W + (size_t)s * BP_K) = o;
}

// ===========================================================================
// Per-iteration kernels, all sequential-write:
// k_reduce (node-shaped): S[i] = sum_row(log msgs) + log prior. Sequential.
// k_emit (slot-shaped, PULL): Wn[s] = norm(max(exp(S[oth]-Wc[rev]),eps)@psi).
//   RO read sequential; Wc[rev] 16B gather (L3); S gather (L2); Wn seq store.
// ===========================================================================

__global__ void __launch_bounds__(256) k_reduce(
        const _Float16* __restrict__ Wc, const int* __restrict__ row,
        const float* __restrict__ LP, float* __restrict__ S, int n) {
    int half = threadIdx.x >> 5;
    int sl = threadIdx.x & 31;
    int i = blockIdx.x * 8 + half;
    if (i >= n) return;

    int r0 = row[i];
    int r1 = row[i + 1];

    float s[BP_K];
#pragma unroll
    for (int k = 0; k < BP_K; ++k) s[k] = 0.0f;

    for (int j = r0 + sl; j < r1; j += 32) {
        half8 h = *(const half8*)(Wc + (size_t)j * BP_K);
#pragma unroll
        for (int k = 0; k < BP_K; ++k) s[k] += (float)h[k] - LOG_C;
    }

#pragma unroll
    for (int off = 16; off >= 1; off >>= 1) {
#pragma unroll
        for (int k = 0; k < BP_K; ++k) s[k] += __shfl_xor(s[k], off);
    }

    if (sl == 0) {
        const float4* lp4 = (const float4*)(LP + (size_t)i * BP_K);
        float4 la = lp4[0], lb = lp4[1];
        float4* o4 = (float4*)(S + (size_t)i * BP_K);
        o4[0] = {s[0] + la.x, s[1] + la.y, s[2] + la.z, s[3] + la.w};
        o4[1] = {s[4] + lb.x, s[5] + lb.y, s[6] + lb.z, s[7] + lb.w};
    }
}

__global__ void __launch_bounds__(256) k_emit(
        const _Float16* __restrict__ Wc, const float* __restrict__ S,
        const int2* __restrict__ RO,
        const float* __restrict__ potential, _Float16* __restrict__ Wn, int E) {
    __shared__ float psi[BP_K * BP_K];
    if (threadIdx.x < BP_K * BP_K) psi[threadIdx.x] = expf(potential[threadIdx.x]);
    __syncthreads();

    int s = blockIdx.x * blockDim.x + threadIdx.x;
    if (s >= E) return;

    int2 ro = RO[s];                      // (rev slot, other-end node)
    half8 h = *(const half8*)(Wc + (size_t)ro.x * BP_K);   // gather
    const float4* s4 = (const float4*)(S + (size_t)ro.y * BP_K);
    float4 sa = s4[0], sb = s4[1];
    float sv[BP_K] = {sa.x, sa.y, sa.z, sa.w, sb.x, sb.y, sb.z, sb.w};

    float bb[BP_K];
#pragma unroll
    for (int k = 0; k < BP_K; ++k) {
        float lm = (float)h[k] - LOG_C;
        bb[k] = fmaxf(__expf(sv[k] - lm), BP_EPS);
    }

    float mn[BP_K];
    float sum = 0.0f;
#pragma unroll
    for (int jj = 0; jj < BP_K; ++jj) {
        float acc = 0.0f;
#pragma unroll
        for (int k = 0; k < BP_K; ++k) acc += bb[k] * psi[k * BP_K + jj];
        mn[jj] = acc;
        sum += acc;
    }
    float inv = 1.0f / fmaxf(sum, BP_EPS);

    half8 o;
#pragma unroll
    for (int jj = 0; jj < BP_K; ++jj)
        o[jj] = (_Float16)(__logf(fmaxf(mn[jj] * inv, BP_EPS)) + LOG_C);

    *(half8*)(Wn + (size_t)s * BP_K) = o;   // SEQUENTIAL store
}

// Final beliefs: sequential row read, normalize with prior (via LP).
__global__ void __launch_bounds__(256) k_belief(
        const _Float16* __restrict__ Wc, const int* __restrict__ row,
        const float* __restrict__ LP, float* __restrict__ out, int n) {
    int half = threadIdx.x >> 5;
    int sl = threadIdx.x & 31;
    int i = blockIdx.x * 8 + half;
    if (i >= n) return;

    int r0 = row[i];
    int r1 = row[i + 1];

    float s[BP_K];
#pragma unroll
    for (int k = 0; k < BP_K; ++k) s[k] = 0.0f;

    for (int j = r0 + sl; j < r1; j += 32) {
        half8 h = *(const half8*)(Wc + (size_t)j * BP_K);
#pragma unroll
        for (int k = 0; k < BP_K; ++k) s[k] += (float)h[k] - LOG_C;
    }

#pragma unroll
    for (int off = 16; off >= 1; off >>= 1) {
#pragma unroll
        for (int k = 0; k < BP_K; ++k) s[k] += __shfl_xor(s[k], off);
    }

    if (sl == 0) {
        const float4* lp4 = (const float4*)(LP + (size_t)i * BP_K);
        float4 la = lp4[0], lb = lp4[1];
        float lp[BP_K] = {la.x, la.y, la.z, la.w, lb.x, lb.y, lb.z, lb.w};
        float b[BP_K];
        float sum = 0.0f;
#pragma unroll
        for (int k = 0; k < BP_K; ++k) {
            b[k] = fmaxf(__expf(s[k] + lp[k]), BP_EPS);
            sum += b[k];
        }
        float inv = 1.0f / fmaxf(sum, BP_EPS);
        float4* o4 = (float4*)(out + (size_t)i * BP_K);
        o4[0] = {b[0] * inv, b[1] * inv, b[2] * inv, b[3] * inv};
        o4[1] = {b[4] * inv, b[5] * inv, b[6] * inv, b[7] * inv};
    }
}

extern "C" void kernel_launch(void* const* d_in, const int* in_sizes, int n_in,
                              void* d_out, int out_size, void* d_ws, size_t ws_size,
                              hipStream_t stream) {
    const float* prior     = (const float*)d_in[0];
    const float* msgs      = (const float*)d_in[1];
    const float* potential = (const float*)d_in[2];
    const int*   src       = (const int*)d_in[3];
    const int*   dst       = (const int*)d_in[4];
    const int ITERS = 5;   // fixed by setup_inputs

    int n  = in_sizes[0] / BP_K;
    int E  = in_sizes[3];
    int Eu = E / 2;
    int nbuck = (n + BNODES - 1) >> BSH;

    char* w = (char*)d_ws;
    _Float16* W1 = (_Float16*)w;   w += (size_t)Eu * 16 * sizeof(_Float16);
    _Float16* W2 = (_Float16*)w;   w += (size_t)Eu * 16 * sizeof(_Float16);
    float* LP    = (float*)w;      w += (size_t)n * BP_K * sizeof(float);
    int*   G     = (int*)w;        w += (size_t)NB1 * nbuck * sizeof(int);
    int*   Gpre  = (int*)w;        w += (size_t)NB1 * nbuck * sizeof(int);
    int*   total = (int*)w;        w += (size_t)nbuck * sizeof(int);
    int*   base  = (int*)w;        w += (size_t)(nbuck + 1) * sizeof(int);
    int*   row   = (int*)w;        w += (size_t)(n + 1) * sizeof(int);
    int2*  RO    = (int2*)w;       w += (size_t)E * sizeof(int2);
    int*   eid   = (int*)w;        w += (size_t)E * sizeof(int);
    float* S     = (float*)w;      w += (size_t)n * BP_K * sizeof(float);
    // items + pos alias W2: both dead before W2's first write (emit #1).
    int2*  items = (int2*)W2;
    int*   pos   = (int*)((char*)W2 + (size_t)E * sizeof(int2));

    float* out = (float*)d_out;

    dim3 blk(256);
    dim3 grdEu((Eu + 255) / 256);
    dim3 grdE((E + 255) / 256);
    dim3 grdNode((n + 7) / 8);     // 8 half-waves/block, half-wave per node
    size_t lds_hist = (size_t)nbuck * sizeof(int);

    // --- build: bucket-grouping CSR + RO/eid maps, no global atomics ---
    k_hist   <<<NB1, blk, lds_hist, stream>>>(src, dst, G, Eu, nbuck);
    k_scanG  <<<nbuck, NB1, 0, stream>>>(G, Gpre, total, nbuck);
    k_scanT  <<<1, 1024, 0, stream>>>(total, base, nbuck, row + n, E);
    k_scatter<<<NB1, blk, lds_hist, stream>>>(src, dst, Gpre, base, items, Eu, nbuck);
    k_csr    <<<nbuck, blk, 0, stream>>>(items, base, row, pos, eid, n, Eu);
    k_ro     <<<grdEu, blk, 0, stream>>>(pos, src, dst, RO, Eu);
    k_lp     <<<(n * BP_K + 255) / 256, blk, 0, stream>>>(prior, LP, n * BP_K);

    // --- one-time gather-permute: edge-order fp32 -> slot-order fp16 log ---
    k_perm<<<grdE, blk, 0, stream>>>(msgs, eid, W1, E);

    // --- 5 uniform iterations: node-shaped reduce + slot-shaped pull-emit ---
    _Float16* cur = W1;
    _Float16* nxt = W2;
    for (int it = 0; it < ITERS; ++it) {
        k_reduce<<<grdNode, blk, 0, stream>>>(cur, row, LP, S, n);
        k_emit  <<<grdE, blk, 0, stream>>>(cur, S, RO, potential, nxt, E);
        _Float16* tmp = cur; cur = nxt; nxt = tmp;
    }

    // --- final beliefs: sequential read of W ---
    k_belief<<<grdNode, blk, 0, stream>>>(cur, row, LP, out, n);
}

// Round 10
// 869.347 us; speedup vs baseline: 1.1567x; 1.1567x over previous
//
#include <hip/hip_runtime.h>
#include <hip/hip_fp16.h>

#define BP_EPS 1e-12f
#define BP_K 8
#define LOG_C 2.0f      // centering offset: stored = log(m) + LOG_C
#define BSH 6           // nodes per bucket = 64
#define BNODES 64
#define NB1 512         // edge chunks (blocks) for hist + scatter
#define BB_SH 16        // slots per bin = 65536 -> 1 MB of fp16 messages/bin
#define MAXBINS 64      // E=3.2M -> 49 bins

typedef __attribute__((ext_vector_type(8))) _Float16 half8;

// ===========================================================================
// Slot space: CSR order by node (slot s at node i holds the message INTO i).
// rev[s] = slot of the reverse directed edge. mid arrays hold messages in
// BINNED order: grouped by bin(consumer slot) (bin = 64K slots = 1 MB),
// sub-ordered by producer chunk -> producer-side stores are line-granular
// runs; consumer-side gathers are random only within an L2-resident 1 MB
// window (+ XCD swizzle keeps each XCD's window in its own L2).
// prod_pos[t]: where the message produced at slot t goes in mid.
// cons_pos[s]: where slot s's current message lives in mid
//              (= prod_pos[rev[s]]).
// ===========================================================================

__global__ void k_hist(const int* __restrict__ src, const int* __restrict__ dst,
                       int* __restrict__ G, int Eu, int nbuck) {
    extern __shared__ int h[];
    for (int i = threadIdx.x; i < nbuck; i += blockDim.x) h[i] = 0;
    __syncthreads();
    int per = (Eu + NB1 - 1) / NB1;
    int s0 = blockIdx.x * per;
    int s1 = min(s0 + per, Eu);
    for (int e = s0 + threadIdx.x; e < s1; e += blockDim.x) {
        atomicAdd(&h[src[e] >> BSH], 1);
        atomicAdd(&h[dst[e] >> BSH], 1);
    }
    __syncthreads();
    for (int b = threadIdx.x; b < nbuck; b += blockDim.x)
        G[blockIdx.x * nbuck + b] = h[b];
}

__global__ void k_scanG(const int* __restrict__ G, int* __restrict__ Gpre,
                        int* __restrict__ total, int nbuck) {
    __shared__ int buf[NB1];
    int b = blockIdx.x;
    int t = threadIdx.x;
    int v = G[t * nbuck + b];
    buf[t] = v;
    __syncthreads();
    for (int off = 1; off < NB1; off <<= 1) {
        int x = (t >= off) ? buf[t - off] : 0;
        __syncthreads();
        buf[t] += x;
        __syncthreads();
    }
    Gpre[b * NB1 + t] = buf[t] - v;
    if (t == NB1 - 1) total[b] = buf[t];
}

__global__ void k_scanT(const int* __restrict__ total, int* __restrict__ base,
                        int nbuck, int* __restrict__ row_n, int E) {
    __shared__ int buf[1024];
    int t = threadIdx.x;
    int carry = 0;
    for (int s = 0; s < nbuck; s += 1024) {
        int i = s + t;
        int v = (i < nbuck) ? total[i] : 0;
        buf[t] = v;
        __syncthreads();
        for (int off = 1; off < 1024; off <<= 1) {
            int x = (t >= off) ? buf[t - off] : 0;
            __syncthreads();
            buf[t] += x;
            __syncthreads();
        }
        if (i < nbuck) base[i] = carry + buf[t] - v;
        carry += buf[1023];
        __syncthreads();
    }
    if (t == 0) { base[nbuck] = carry; *row_n = E; }
}

__global__ void k_scatter(const int* __restrict__ src, const int* __restrict__ dst,
                          const int* __restrict__ Gpre, const int* __restrict__ base,
                          int2* __restrict__ items, int Eu, int nbuck) {
    extern __shared__ int cur[];
    int blk = blockIdx.x;
    for (int i = threadIdx.x; i < nbuck; i += blockDim.x)
        cur[i] = base[i] + Gpre[i * NB1 + blk];
    __syncthreads();
    int per = (Eu + NB1 - 1) / NB1;
    int s0 = blk * per;
    int s1 = min(s0 + per, Eu);
    for (int e = s0 + threadIdx.x; e < s1; e += blockDim.x) {
        int u = src[e], v = dst[e];
        int pu = atomicAdd(&cur[u >> BSH], 1);
        items[pu] = make_int2(u, (e << 1) | 1);
        int pv = atomicAdd(&cur[v >> BSH], 1);
        items[pv] = make_int2(v, (e << 1) | 0);
    }
}

// bucket -> per-node CSR; emit pos[payload] = slot, eid[slot] = msgs row id.
__global__ void k_csr(const int2* __restrict__ items, const int* __restrict__ base,
                      int* __restrict__ row, int* __restrict__ pos,
                      int* __restrict__ eid, int n, int Eu) {
    __shared__ int deg[BNODES];
    __shared__ int cur[BNODES];
    int b = blockIdx.x;
    int lo = base[b], hi = base[b + 1];
    int node0 = b << BSH;
    if (threadIdx.x < BNODES) deg[threadIdx.x] = 0;
    __syncthreads();
    for (int i = lo + threadIdx.x; i < hi; i += blockDim.x)
        atomicAdd(&deg[items[i].x - node0], 1);
    __syncthreads();
    if (threadIdx.x == 0) {
        int acc = 0;
        for (int t = 0; t < BNODES; ++t) { int d = deg[t]; deg[t] = acc; acc += d; }
    }
    __syncthreads();
    if (threadIdx.x < BNODES) {
        int node = node0 + threadIdx.x;
        if (node < n) row[node] = lo + deg[threadIdx.x];
        cur[threadIdx.x] = deg[threadIdx.x];
    }
    __syncthreads();
    for (int i = lo + threadIdx.x; i < hi; i += blockDim.x) {
        int2 x = items[i];
        int p = atomicAdd(&cur[x.x - node0], 1);
        int slot = lo + p;
        pos[x.y] = slot;
        eid[slot] = (x.y >> 1) + (x.y & 1) * Eu;
    }
}

// rev from pos pairs: slots pos[2e] and pos[2e+1] are mutual reverses.
__global__ void k_rev(const int* __restrict__ pos, int* __restrict__ rev, int Eu) {
    int e = blockIdx.x * blockDim.x + threadIdx.x;
    if (e < Eu) {
        int2 p = ((const int2*)pos)[e];
        rev[p.x] = p.y;
        rev[p.y] = p.x;
    }
}

// ---- binning counting-sort: prod_pos[t] = bbase[bin(rev[t])] + rank -------
__global__ void k_bhist(const int* __restrict__ rev, int* __restrict__ BG,
                        int E, int nbins) {
    __shared__ int h[MAXBINS];
    if (threadIdx.x < nbins) h[threadIdx.x] = 0;
    __syncthreads();
    int t = blockIdx.x * 256 + threadIdx.x;
    if (t < E) atomicAdd(&h[rev[t] >> BB_SH], 1);
    __syncthreads();
    if (threadIdx.x < nbins) BG[blockIdx.x * nbins + threadIdx.x] = h[threadIdx.x];
}

__global__ void k_bscan(const int* __restrict__ BG, int* __restrict__ BGpre,
                        int* __restrict__ btot, int nch, int nbins) {
    __shared__ int buf[1024];
    int b = blockIdx.x;
    int t = threadIdx.x;
    int carry = 0;
    for (int s = 0; s < nch; s += 1024) {
        int c = s + t;
        int v = (c < nch) ? BG[c * nbins + b] : 0;
        buf[t] = v;
        __syncthreads();
        for (int off = 1; off < 1024; off <<= 1) {
            int x = (t >= off) ? buf[t - off] : 0;
            __syncthreads();
            buf[t] += x;
            __syncthreads();
        }
        if (c < nch) BGpre[c * nbins + b] = carry + buf[t] - v;
        carry += buf[1023];
        __syncthreads();
    }
    if (t == 0) btot[b] = carry;
}

__global__ void k_bbase(const int* __restrict__ btot, int* __restrict__ bbase,
                        int nbins) {
    if (threadIdx.x == 0 && blockIdx.x == 0) {
        int acc = 0;
        for (int b = 0; b < nbins; ++b) { bbase[b] = acc; acc += btot[b]; }
        bbase[nbins] = acc;
    }
}

__global__ void k_bscatter(const int* __restrict__ rev, const int* __restrict__ bbase,
                           const int* __restrict__ BGpre, int* __restrict__ prod,
                           int E, int nbins) {
    __shared__ int cur[MAXBINS];
    if (threadIdx.x < nbins)
        cur[threadIdx.x] = bbase[threadIdx.x] + BGpre[blockIdx.x * nbins + threadIdx.x];
    __syncthreads();
    int t = blockIdx.x * 256 + threadIdx.x;
    if (t < E) {
        int b = rev[t] >> BB_SH;
        prod[t] = atomicAdd(&cur[b], 1);
    }
}

// cons_pos[s] = prod_pos[rev[s]] (one random 4B gather per slot, one-time).
__global__ void k_cpos(const int* __restrict__ rev, const int* __restrict__ prod,
                       int* __restrict__ cons, int E) {
    int s = blockIdx.x * blockDim.x + threadIdx.x;
    if (s < E) cons[s] = prod[rev[s]];
}

// LP[i][k] = log(max(prior, eps)).
__global__ void k_lp(const float* __restrict__ prior, float* __restrict__ LP, int n8) {
    int i = blockIdx.x * blockDim.x + threadIdx.x;
    if (i < n8) LP[i] = __logf(fmaxf(prior[i], BP_EPS));
}

// ---- shared emit math: new msg = norm(max(exp(s-lm),eps) @ psi), log, fp16.
__device__ inline half8 bp_emit(const float* s, const float* lm,
                                const float* psi) {
    float bb[BP_K];
#pragma unroll
    for (int k = 0; k < BP_K; ++k)
        bb[k] = fmaxf(__expf(s[k] - lm[k]), BP_EPS);
    float mn[BP_K];
    float sum = 0.0f;
#pragma unroll
    for (int jj = 0; jj < BP_K; ++jj) {
        float acc = 0.0f;
#pragma unroll
        for (int k = 0; k < BP_K; ++k) acc += bb[k] * psi[k * BP_K + jj];
        mn[jj] = acc;
        sum += acc;
    }
    float inv = 1.0f / fmaxf(sum, BP_EPS);
    half8 o;
#pragma unroll
    for (int jj = 0; jj < BP_K; ++jj)
        o[jj] = (_Float16)(__logf(fmaxf(mn[jj] * inv, BP_EPS)) + LOG_C);
    return o;
}

// ===========================================================================
// Fused iteration (half-wave per node): gather row's messages (iter 1: fp32
// input via eid; steady: mid via cons_pos, L2-window-local), cache trips 0/1
// in registers, shuffle-reduce S (+log prior), then emit each cached slot's
// new message to mid_next[prod_pos[j]] (line-grouped stores, no atomics).
// ===========================================================================

__global__ void __launch_bounds__(256) k_step_first(
        const float* __restrict__ msgs, const int* __restrict__ eid,
        const int* __restrict__ row, const int* __restrict__ prod,
        const float* __restrict__ LP, const float* __restrict__ potential,
        _Float16* __restrict__ Mn, int n) {
    __shared__ float psi[BP_K * BP_K];
    if (threadIdx.x < BP_K * BP_K) psi[threadIdx.x] = expf(potential[threadIdx.x]);
    __syncthreads();

    int half = threadIdx.x >> 5;
    int sl = threadIdx.x & 31;
    int i = blockIdx.x * 8 + half;
    if (i >= n) return;

    int r0 = row[i];
    int r1 = row[i + 1];
    int j0 = r0 + sl;
    int j1 = j0 + 32;
    bool h0 = j0 < r1;
    bool h1 = j1 < r1;

    float s[BP_K];
#pragma unroll
    for (int k = 0; k < BP_K; ++k) s[k] = 0.0f;

    float lm0[BP_K], lm1[BP_K];
    int q0 = 0, q1 = 0;

#define LOADF(J, LM)                                                          \
    {                                                                         \
        int id = eid[J];                                                      \
        const float4* m4 = (const float4*)(msgs + (size_t)id * BP_K);         \
        float4 x = m4[0], y = m4[1];                                          \
        float v[BP_K] = {x.x, x.y, x.z, x.w, y.x, y.y, y.z, y.w};             \
        _Pragma("unroll")                                                     \
        for (int k = 0; k < BP_K; ++k) LM[k] = __logf(fmaxf(v[k], BP_EPS));   \
    }

    if (h0) {
        q0 = prod[j0];
        LOADF(j0, lm0);
#pragma unroll
        for (int k = 0; k < BP_K; ++k) s[k] += lm0[k];
    }
    if (h1) {
        q1 = prod[j1];
        LOADF(j1, lm1);
#pragma unroll
        for (int k = 0; k < BP_K; ++k) s[k] += lm1[k];
    }
    for (int j = j0 + 64; j < r1; j += 32) {
        float t[BP_K];
        LOADF(j, t);
#pragma unroll
        for (int k = 0; k < BP_K; ++k) s[k] += t[k];
    }

#pragma unroll
    for (int off = 16; off >= 1; off >>= 1) {
#pragma unroll
        for (int k = 0; k < BP_K; ++k) s[k] += __shfl_xor(s[k], off);
    }
    {
        const float4* lp4 = (const float4*)(LP + (size_t)i * BP_K);
        float4 la = lp4[0], lb = lp4[1];
        s[0] += la.x; s[1] += la.y; s[2] += la.z; s[3] += la.w;
        s[4] += lb.x; s[5] += lb.y; s[6] += lb.z; s[7] += lb.w;
    }

    if (h0) *(half8*)(Mn + (size_t)q0 * BP_K) = bp_emit(s, lm0, psi);
    if (h1) *(half8*)(Mn + (size_t)q1 * BP_K) = bp_emit(s, lm1, psi);
    for (int j = j0 + 64; j < r1; j += 32) {
        float t[BP_K];
        LOADF(j, t);
        *(half8*)(Mn + (size_t)prod[j] * BP_K) = bp_emit(s, t, psi);
    }
#undef LOADF
}

__global__ void __launch_bounds__(256) k_step(
        const _Float16* __restrict__ Mc, const int* __restrict__ row,
        const int* __restrict__ cons, const int* __restrict__ prod,
        const float* __restrict__ LP, const float* __restrict__ potential,
        _Float16* __restrict__ Mn, int n, int nwg) {
    __shared__ float psi[BP_K * BP_K];
    if (threadIdx.x < BP_K * BP_K) psi[threadIdx.x] = expf(potential[threadIdx.x]);
    __syncthreads();

    // bijective XCD swizzle (m204): each XCD works a contiguous node range
    // -> its mid-gather window stays in its own L2.
    int bid = blockIdx.x;
    int q = nwg >> 3, r = nwg & 7;
    int x = bid & 7, o = bid >> 3;
    int wg = (x < r ? x * (q + 1) : r * (q + 1) + (x - r) * q) + o;

    int half = threadIdx.x >> 5;
    int sl = threadIdx.x & 31;
    int i = wg * 8 + half;
    if (i >= n) return;

    int r0 = row[i];
    int r1 = row[i + 1];
    int j0 = r0 + sl;
    int j1 = j0 + 32;
    bool h0 = j0 < r1;
    bool h1 = j1 < r1;

    float s[BP_K];
#pragma unroll
    for (int k = 0; k < BP_K; ++k) s[k] = 0.0f;

    float lm0[BP_K], lm1[BP_K];
    int q0 = 0, q1 = 0;

    if (h0) {
        q0 = prod[j0];
        half8 m = *(const half8*)(Mc + (size_t)cons[j0] * BP_K);
#pragma unroll
        for (int k = 0; k < BP_K; ++k) { lm0[k] = (float)m[k] - LOG_C; s[k] += lm0[k]; }
    }
    if (h1) {
        q1 = prod[j1];
        half8 m = *(const half8*)(Mc + (size_t)cons[j1] * BP_K);
#pragma unroll
        for (int k = 0; k < BP_K; ++k) { lm1[k] = (float)m[k] - LOG_C; s[k] += lm1[k]; }
    }
    for (int j = j0 + 64; j < r1; j += 32) {
        half8 m = *(const half8*)(Mc + (size_t)cons[j] * BP_K);
#pragma unroll
        for (int k = 0; k < BP_K; ++k) s[k] += (float)m[k] - LOG_C;
    }

#pragma unroll
    for (int off = 16; off >= 1; off >>= 1) {
#pragma unroll
        for (int k = 0; k < BP_K; ++k) s[k] += __shfl_xor(s[k], off);
    }
    {
        const float4* lp4 = (const float4*)(LP + (size_t)i * BP_K);
        float4 la = lp4[0], lb = lp4[1];
        s[0] += la.x; s[1] += la.y; s[2] += la.z; s[3] += la.w;
        s[4] += lb.x; s[5] += lb.y; s[6] += lb.z; s[7] += lb.w;
    }

    if (h0) *(half8*)(Mn + (size_t)q0 * BP_K) = bp_emit(s, lm0, psi);
    if (h1) *(half8*)(Mn + (size_t)q1 * BP_K) = bp_emit(s, lm1, psi);
    for (int j = j0 + 64; j < r1; j += 32) {
        half8 m = *(const half8*)(Mc + (size_t)cons[j] * BP_K);
        float t[BP_K];
#pragma unroll
        for (int k = 0; k < BP_K; ++k) t[k] = (float)m[k] - LOG_C;
        *(half8*)(Mn + (size_t)prod[j] * BP_K) = bp_emit(s, t, psi);
    }
}

// Final beliefs: gather mid via cons_pos (L2-windowed), normalize with prior.
__global__ void __launch_bounds__(256) k_belief(
        const _Float16* __restrict__ Mc, const int* __restrict__ row,
        const int* __restrict__ cons, const float* __restrict__ LP,
        float* __restrict__ out, int n, int nwg) {
    int bid = blockIdx.x;
    int q = nwg >> 3, r = nwg & 7;
    int x = bid & 7, o = bid >> 3;
    int wg = (x < r ? x * (q + 1) : r * (q + 1) + (x - r) * q) + o;

    int half = threadIdx.x >> 5;
    int sl = threadIdx.x & 31;
    int i = wg * 8 + half;
    if (i >= n) return;

    int r0 = row[i];
    int r1 = row[i + 1];

    float s[BP_K];
#pragma unroll
    for (int k = 0; k < BP_K; ++k) s[k] = 0.0f;

    for (int j = r0 + sl; j < r1; j += 32) {
        half8 m = *(const half8*)(Mc + (size_t)cons[j] * BP_K);
#pragma unroll
        for (int k = 0; k < BP_K; ++k) s[k] += (float)m[k] - LOG_C;
    }

#pragma unroll
    for (int off = 16; off >= 1; off >>= 1) {
#pragma unroll
        for (int k = 0; k < BP_K; ++k) s[k] += __shfl_xor(s[k], off);
    }

    if (sl == 0) {
        const float4* lp4 = (const float4*)(LP + (size_t)i * BP_K);
        float4 la = lp4[0], lb = lp4[1];
        float lp[BP_K] = {la.x, la.y, la.z, la.w, lb.x, lb.y, lb.z, lb.w};
        float b[BP_K];
        float sum = 0.0f;
#pragma unroll
        for (int k = 0; k < BP_K; ++k) {
            b[k] = fmaxf(__expf(s[k] + lp[k]), BP_EPS);
            sum += b[k];
        }
        float inv = 1.0f / fmaxf(sum, BP_EPS);
        float4* o4 = (float4*)(out + (size_t)i * BP_K);
        o4[0] = {b[0] * inv, b[1] * inv, b[2] * inv, b[3] * inv};
        o4[1] = {b[4] * inv, b[5] * inv, b[6] * inv, b[7] * inv};
    }
}

extern "C" void kernel_launch(void* const* d_in, const int* in_sizes, int n_in,
                              void* d_out, int out_size, void* d_ws, size_t ws_size,
                              hipStream_t stream) {
    const float* prior     = (const float*)d_in[0];
    const float* msgs      = (const float*)d_in[1];
    const float* potential = (const float*)d_in[2];
    const int*   src       = (const int*)d_in[3];
    const int*   dst       = (const int*)d_in[4];
    const int ITERS = 5;   // fixed by setup_inputs

    int n  = in_sizes[0] / BP_K;
    int E  = in_sizes[3];
    int Eu = E / 2;
    int nbuck = (n + BNODES - 1) >> BSH;
    int NCH   = (E + 255) / 256;
    int nbins = (E + (1 << BB_SH) - 1) >> BB_SH;   // 49 for E=3.2M

    char* w = (char*)d_ws;
    _Float16* M1 = (_Float16*)w;  w += (size_t)E * BP_K * sizeof(_Float16);
    _Float16* M2 = (_Float16*)w;  w += (size_t)E * BP_K * sizeof(_Float16);
    float* LP    = (float*)w;     w += (size_t)n * BP_K * sizeof(float);
    int*   G     = (int*)w;       w += (size_t)NB1 * nbuck * sizeof(int);
    int*   Gpre  = (int*)w;       w += (size_t)NB1 * nbuck * sizeof(int);
    int*   total = (int*)w;       w += (size_t)nbuck * sizeof(int);
    int*   base  = (int*)w;       w += (size_t)(nbuck + 1) * sizeof(int);
    int*   row   = (int*)w;       w += (size_t)(n + 1) * sizeof(int);
    int*   prod  = (int*)w;       w += (size_t)E * sizeof(int);
    int*   cons  = (int*)w;       w += (size_t)E * sizeof(int);
    int*   BG    = (int*)w;       w += (size_t)NCH * nbins * sizeof(int);
    int*   BGpre = (int*)w;       w += (size_t)NCH * nbins * sizeof(int);
    int*   btot  = (int*)w;       w += (size_t)nbins * sizeof(int);
    int*   bbase = (int*)w;       w += (size_t)(nbins + 1) * sizeof(int);
    // Aliases (build-time only, dead before their hosts are first written):
    //  rev -> M1 (M1 first written by k_step_first, after build)
    //  items/pos/eid -> M2 (M2 first written by k_step at iteration 2)
    int*   rev   = (int*)M1;
    int2*  items = (int2*)M2;
    int*   pos   = (int*)((char*)M2 + (size_t)E * sizeof(int2));
    int*   eid   = (int*)((char*)M2 + (size_t)E * sizeof(int2) + (size_t)E * sizeof(int));

    float* out = (float*)d_out;

    dim3 blk(256);
    dim3 grdEu((Eu + 255) / 256);
    dim3 grdE((E + 255) / 256);
    int  nwg = (n + 7) / 8;
    dim3 grdNode(nwg);             // 8 half-waves/block, half-wave per node
    size_t lds_hist = (size_t)nbuck * sizeof(int);

    // --- build: CSR + rev + binning counting-sort (prod/cons), no global atomics ---
    k_hist    <<<NB1, blk, lds_hist, stream>>>(src, dst, G, Eu, nbuck);
    k_scanG   <<<nbuck, NB1, 0, stream>>>(G, Gpre, total, nbuck);
    k_scanT   <<<1, 1024, 0, stream>>>(total, base, nbuck, row + n, E);
    k_scatter <<<NB1, blk, lds_hist, stream>>>(src, dst, Gpre, base, items, Eu, nbuck);
    k_csr     <<<nbuck, blk, 0, stream>>>(items, base, row, pos, eid, n, Eu);
    k_rev     <<<grdEu, blk, 0, stream>>>(pos, rev, Eu);
    k_bhist   <<<NCH, blk, 0, stream>>>(rev, BG, E, nbins);
    k_bscan   <<<nbins, 1024, 0, stream>>>(BG, BGpre, btot, NCH, nbins);
    k_bbase   <<<1, 1, 0, stream>>>(btot, bbase, nbins);
    k_bscatter<<<NCH, blk, 0, stream>>>(rev, bbase, BGpre, prod, E, nbins);
    k_cpos    <<<grdE, blk, 0, stream>>>(rev, prod, cons, E);
    k_lp      <<<(n * BP_K + 255) / 256, blk, 0, stream>>>(prior, LP, n * BP_K);

    // --- iteration 1: fused gather of fp32 input msgs -> binned mid M1 ---
    k_step_first<<<grdNode, blk, 0, stream>>>(msgs, eid, row, prod, LP,
                                              potential, M1, n);

    // --- iterations 2..5: fused reduce+emit over binned mid (ping-pong) ---
    _Float16* cur = M1;
    _Float16* nxt = M2;
    for (int it = 1; it < ITERS; ++it) {
        k_step<<<grdNode, blk, 0, stream>>>(cur, row, cons, prod, LP,
                                            potential, nxt, n, nwg);
        _Float16* tmp = cur; cur = nxt; nxt = tmp;
    }

    // --- final beliefs: gather mid via cons_pos ---
    k_belief<<<grdNode, blk, 0, stream>>>(cur, row, cons, LP, out, n, nwg);
}